// Round 2
// baseline (148.110 us; speedup 1.0000x reference)
//
#include <hip/hip_runtime.h>
#include <cstddef>

// ---------------------------------------------------------------------------
// B=2, N=2048, C=1024, H=16, Dh=64, scale = Dh//H = 4
// 4-launch ALL-FP16 pipeline:
//   split_all:  x, qkv_w, proj_w -> fp16 (also zeroes sall; one launch)
//   gemm_mfma:  qkv GEMM, 128x128 tile, BK=64 two-plane; v-blocks also
//               atomically accumulate S_all column sums (fp32) in epilogue
//   attn_mfma:  S=QK^T fp16 MFMA, 128 q-rows/block (512 thr, 8 waves),
//               PER-WAVE 64-wide K-window, exact full-row softmax with
//               masked-logit (=1e-9) fold, P fp16 -> PV MFMA vs LDS V^T
//   gemm_proj:  64x128 tiles, BK=128 four-plane (8 iters x 32 MFMA)
// ---------------------------------------------------------------------------

typedef _Float16 f16x8 __attribute__((ext_vector_type(8)));
typedef float    f32x4 __attribute__((ext_vector_type(4)));

#define MFMA16(a, b, c) __builtin_amdgcn_mfma_f32_16x16x32_f16((a), (b), (c), 0, 0, 0)

__device__ __forceinline__ void gl_lds16(const void* g, void* l) {
    __builtin_amdgcn_global_load_lds(
        (const __attribute__((address_space(1))) void*)g,
        (__attribute__((address_space(3))) void*)l, 16, 0, 0);
}

__device__ __forceinline__ ushort f2h(float f) {
    _Float16 h = (_Float16)f;
    return *(ushort*)&h;
}

// ---------------------------------------------------------------------------
// fused fp32 -> fp16 conversion for all three tensors + sall zeroing.
// ---------------------------------------------------------------------------
__global__ void split_all(const float* __restrict__ x,
                          const float* __restrict__ qkvw,
                          const float* __restrict__ projw,
                          ushort* __restrict__ x16,
                          ushort* __restrict__ w16,
                          ushort* __restrict__ pw16,
                          float* __restrict__ sall)
{
    const int i = blockIdx.x * 256 + threadIdx.x;
    if (i < 512) ((float4*)sall)[i] = make_float4(0.f, 0.f, 0.f, 0.f);
    const float* src; ushort* dst; int j;
    if (i < 1048576)      { src = x;     dst = x16;  j = i; }
    else if (i < 1835008) { src = qkvw;  dst = w16;  j = i - 1048576; }
    else                  { src = projw; dst = pw16; j = i - 1835008; }

    float4 v = ((const float4*)src)[j];
    ((ushort4*)dst)[j] = make_ushort4(f2h(v.x), f2h(v.y), f2h(v.z), f2h(v.w));
}

// ---------------------------------------------------------------------------
// qkv MFMA GEMM: 128x128 tile, BK=64 two-plane (32 KB). 16 iters x 32 MFMA.
// Scatter fp16 into q|k|v [3][B,H,N,64]. v-blocks (n0>=2048) also reduce
// their 64-row column partials and atomicAdd into sall[32][64] (fp32).
// ---------------------------------------------------------------------------
__global__ __launch_bounds__(256, 3) void gemm_mfma(
    const ushort* __restrict__ A_g, const ushort* __restrict__ W_g,
    ushort* __restrict__ out16, float* __restrict__ sall, int K)
{
    __shared__ ushort smem[16384];
    ushort* AS0 = smem;
    ushort* AS1 = smem + 4096;
    ushort* WS0 = smem + 8192;
    ushort* WS1 = smem + 12288;

    const int tid  = threadIdx.x;
    const int wid  = tid >> 6;
    const int lane = tid & 63;
    const int quad = lane >> 4;
    const int cl   = lane & 15;
    const int m0 = blockIdx.y * 128;
    const int n0 = blockIdx.x * 128;
    const int wm = (wid & 1) * 64;
    const int wn = (wid >> 1) * 64;

    const int srow = lane >> 2;
    const int scol = (lane & 3) * 8;

    const ushort* src = (wid < 2) ? A_g : W_g;
    ushort* dst = smem + wid * 4096;
    const int r0 = (wid < 2) ? m0 : n0;
    const int cofs = (wid & 1) * 32;

    f32x4 acc[4][4];
#pragma unroll
    for (int i = 0; i < 4; ++i)
#pragma unroll
        for (int j = 0; j < 4; ++j) acc[i][j] = (f32x4){0.f, 0.f, 0.f, 0.f};

    for (int k0 = 0; k0 < K; k0 += 64) {
#pragma unroll
        for (int c = 0; c < 8; ++c)
            gl_lds16(src + (size_t)(r0 + c * 16 + srow) * K + k0 + cofs + scol,
                     dst + c * 512);
        __syncthreads();

        f16x8 a0[4], w0[4];
#pragma unroll
        for (int i = 0; i < 4; ++i) {
            a0[i] = ((const f16x8*)AS0)[(wm + i * 16 + cl) * 4 + quad];
            w0[i] = ((const f16x8*)WS0)[(wn + i * 16 + cl) * 4 + quad];
        }
#pragma unroll
        for (int mi = 0; mi < 4; ++mi)
#pragma unroll
            for (int ni = 0; ni < 4; ++ni)
                acc[mi][ni] = MFMA16(a0[mi], w0[ni], acc[mi][ni]);

        f16x8 a1[4], w1[4];
#pragma unroll
        for (int i = 0; i < 4; ++i) {
            a1[i] = ((const f16x8*)AS1)[(wm + i * 16 + cl) * 4 + quad];
            w1[i] = ((const f16x8*)WS1)[(wn + i * 16 + cl) * 4 + quad];
        }
#pragma unroll
        for (int mi = 0; mi < 4; ++mi)
#pragma unroll
            for (int ni = 0; ni < 4; ++ni)
                acc[mi][ni] = MFMA16(a1[mi], w1[ni], acc[mi][ni]);
        __syncthreads();
    }

#pragma unroll
    for (int mi = 0; mi < 4; ++mi)
#pragma unroll
        for (int r = 0; r < 4; ++r) {
            const int gm = m0 + wm + mi * 16 + quad * 4 + r;
            const int b  = gm >> 11;
            const int nn = gm & 2047;
#pragma unroll
            for (int ni = 0; ni < 4; ++ni) {
                const int gn = n0 + wn + ni * 16 + cl;
                const int s  = gn >> 10;          // 0:q 1:k 2:v
                const int h  = (gn >> 6) & 15;
                const int dh = gn & 63;
                out16[(size_t)s * 4194304u + (((size_t)b * 16 + h) * 2048 + nn) * 64 + dh]
                    = f2h(acc[mi][ni][r]);
            }
        }

    // v-blocks: S_all partials (wave covers 64 rows, uniform b and h)
    if (n0 >= 2048) {
        const int b = (m0 + wm) >> 11;
        const int h = ((n0 + wn) >> 6) & 15;
#pragma unroll
        for (int ni = 0; ni < 4; ++ni) {
            float ps = 0.f;
#pragma unroll
            for (int mi = 0; mi < 4; ++mi)
#pragma unroll
                for (int r = 0; r < 4; ++r) ps += acc[mi][ni][r];
            ps += __shfl_xor(ps, 16);
            ps += __shfl_xor(ps, 32);
            if (quad == 0)
                atomicAdd(&sall[(b * 16 + h) * 64 + ni * 16 + cl], ps);
        }
    }
}

// ---------------------------------------------------------------------------
// Proj GEMM, 64x128 tiles (512 blocks = 2/CU), BK=128 four-plane (48 KB LDS).
// ---------------------------------------------------------------------------
__global__ __launch_bounds__(256, 2) void gemm_proj(
    const ushort* __restrict__ A_g, const ushort* __restrict__ W_g,
    const float* __restrict__ bias, float* __restrict__ out)
{
    const int K = 1024, Nout = 1024;
    __shared__ ushort smem[24576];

    const int tid  = threadIdx.x;
    const int wid  = tid >> 6;
    const int lane = tid & 63;
    const int quad = lane >> 4;
    const int cl   = lane & 15;
    const int m0 = blockIdx.y * 64;
    const int n0 = blockIdx.x * 128;
    const int wm = (wid & 1) * 32;
    const int wn = (wid >> 1) * 64;

    const int srow = lane >> 2;
    const int scol = (lane & 3) * 8;

    f32x4 acc[2][4];
#pragma unroll
    for (int i = 0; i < 2; ++i)
#pragma unroll
        for (int j = 0; j < 4; ++j) acc[i][j] = (f32x4){0.f, 0.f, 0.f, 0.f};

    for (int k0 = 0; k0 < K; k0 += 128) {
#pragma unroll
        for (int c = 0; c < 12; ++c) {
            const int cid = wid * 12 + c;
            const ushort* s; ushort* d; int rr, pl;
            if (cid < 16) {
                pl = cid >> 2;
                const int ch = cid & 3;
                s = A_g; rr = m0 + ch * 16;
                d = smem + pl * 2048 + ch * 512;
            } else {
                const int wc = cid - 16;
                pl = wc >> 3;
                const int ch = wc & 7;
                s = W_g; rr = n0 + ch * 16;
                d = smem + 8192 + pl * 4096 + ch * 512;
            }
            gl_lds16(s + (size_t)(rr + srow) * K + k0 + pl * 32 + scol, d);
        }
        __syncthreads();

#pragma unroll
        for (int pl = 0; pl < 4; ++pl) {
            const ushort* ASp = smem + pl * 2048;
            const ushort* WSp = smem + 8192 + pl * 4096;
            f16x8 a[2], w[4];
#pragma unroll
            for (int i = 0; i < 2; ++i)
                a[i] = ((const f16x8*)ASp)[(wm + i * 16 + cl) * 4 + quad];
#pragma unroll
            for (int i = 0; i < 4; ++i)
                w[i] = ((const f16x8*)WSp)[(wn + i * 16 + cl) * 4 + quad];
#pragma unroll
            for (int mi = 0; mi < 2; ++mi)
#pragma unroll
                for (int ni = 0; ni < 4; ++ni)
                    acc[mi][ni] = MFMA16(a[mi], w[ni], acc[mi][ni]);
        }
        __syncthreads();
    }

    float bb[4];
#pragma unroll
    for (int ni = 0; ni < 4; ++ni) bb[ni] = bias[n0 + wn + ni * 16 + cl];
#pragma unroll
    for (int mi = 0; mi < 2; ++mi)
#pragma unroll
        for (int r = 0; r < 4; ++r) {
            const int gm = m0 + wm + mi * 16 + quad * 4 + r;
            float* rowp = out + (size_t)gm * Nout;
#pragma unroll
            for (int ni = 0; ni < 4; ++ni) {
                const int gn = n0 + wn + ni * 16 + cl;
                rowp[gn] = acc[mi][ni][r] + bb[ni];
            }
        }
}

// ---------------------------------------------------------------------------
// MFMA flash-band attention (fp16), per-wave 64-wide K-window.
// Block = one (b,h) x 128 q-rows, 8 waves x 16 rows (512 thr). A wave's rows
// touch only 16+2w+1 <= 57 K-cols; sbase = floor(s_min/8)*8 covers them in 64
// cols (55 <= 56 slack guarantees coverage; sbase <= 112, reads end <= 176).
// VT padded to 180 cols: row stride 360 B keeps PV ds_read_b128 at 2-way
// (free) bank aliasing.
// ---------------------------------------------------------------------------
__global__ __launch_bounds__(512) void attn_mfma(
    const ushort* __restrict__ qg, const ushort* __restrict__ kg,
    const ushort* __restrict__ vg,
    const float* __restrict__ sall,
    ushort* __restrict__ outp,
    const int* __restrict__ epoch_ptr)
{
    const int N = 2048;
    const int w = (epoch_ptr[0] < 15) ? 16 : 20;

    __shared__ ushort Pl[8][16][72];      // per-wave P~ tile (64 cols + pad)
    __shared__ ushort VT[64][180];        // transposed V band [dim][seq]

    const int tid  = threadIdx.x;
    const int wid  = tid >> 6;            // 0..7
    const int lane = tid & 63;
    const int quad = lane >> 4;
    const int cl   = lane & 15;

    const int bh = blockIdx.x >> 4;       // 32 (b,h) x 16 q-blocks
    const int n0 = (blockIdx.x & 15) << 7;
    const int lo = max(0, n0 - w);
    const int wm = wid << 4;              // 0..112
    const int hi = min(N - 1, n0 + 127 + w);
    const int cnt = hi - lo + 1;          // 144..168

    // zero VT cols [128,180) only (cnt >= 144 guarantees cols <144 get filled)
    for (int t = tid; t < 64 * 26; t += 512) {
        const int row = t / 26;
        const int c2  = 128 + (t - row * 26) * 2;
        *(unsigned*)&VT[row][c2] = 0u;
    }
    __syncthreads();    // zero visible before scatter overwrites [128,cnt)

    // scatter V band (coalesced reads) into VT transposed
    for (int t = tid; t < 168 * 8; t += 512) {
        const int s  = t >> 3;
        const int db = (t & 7) * 8;
        if (s < cnt) {
            uint4 vv = *(const uint4*)(vg + (((size_t)bh * N) + lo + s) * 64 + db);
            VT[db + 0][s] = (ushort)(vv.x & 0xffff); VT[db + 1][s] = (ushort)(vv.x >> 16);
            VT[db + 2][s] = (ushort)(vv.y & 0xffff); VT[db + 3][s] = (ushort)(vv.y >> 16);
            VT[db + 4][s] = (ushort)(vv.z & 0xffff); VT[db + 5][s] = (ushort)(vv.z >> 16);
            VT[db + 6][s] = (ushort)(vv.w & 0xffff); VT[db + 7][s] = (ushort)(vv.w >> 16);
        }
    }

    // per-wave K window base (multiple of 8, in VT coordinates)
    const int jminw = max(0, n0 + wm - w);
    const int sbase = ((jminw - lo) >> 3) << 3;

    const ushort* qp = qg + ((size_t)bh * N + n0 + wm + cl) * 64;
    const f16x8 aq0 = *(const f16x8*)(qp + quad * 8);
    const f16x8 aq1 = *(const f16x8*)(qp + 32 + quad * 8);

    f32x4 sacc[4];
#pragma unroll
    for (int ni = 0; ni < 4; ++ni) {
        int krow = lo + sbase + ni * 16 + cl;
        krow = min(krow, N - 1);                 // clamped rows masked later
        const ushort* kp = kg + ((size_t)bh * N + krow) * 64;
        const f16x8 bk0 = *(const f16x8*)(kp + quad * 8);
        const f16x8 bk1 = *(const f16x8*)(kp + 32 + quad * 8);
        f32x4 s = (f32x4){0.f, 0.f, 0.f, 0.f};
        s = MFMA16(aq0, bk0, s);
        s = MFMA16(aq1, bk1, s);
        sacc[ni] = s;
    }
    // fold scale=4 once (exact power of two)
#pragma unroll
    for (int ni = 0; ni < 4; ++ni) sacc[ni] *= 4.0f;

    float pm[4];
#pragma unroll
    for (int r = 0; r < 4; ++r) {
        const int n = n0 + wm + quad * 4 + r;
        const int jlo = max(0, n - w), jhi = min(N - 1, n + w);
        const int bc = jhi - jlo + 1;
        float mx = 1e-9f;
#pragma unroll
        for (int ni = 0; ni < 4; ++ni) {
            const int j = lo + sbase + ni * 16 + cl;
            const bool val = (j >= n - w) && (j <= n + w) && (j < N);
            const float sv = sacc[ni][r];
            if (val) mx = fmaxf(mx, sv);
        }
        mx = fmaxf(mx, __shfl_xor(mx, 1));
        mx = fmaxf(mx, __shfl_xor(mx, 2));
        mx = fmaxf(mx, __shfl_xor(mx, 4));
        mx = fmaxf(mx, __shfl_xor(mx, 8));
        const float em = __expf(1e-9f - mx);
        float e[4];
        float sum = 0.f;
#pragma unroll
        for (int ni = 0; ni < 4; ++ni) {
            const int j = lo + sbase + ni * 16 + cl;
            const bool val = (j >= n - w) && (j <= n + w) && (j < N);
            const float ev = val ? __expf(sacc[ni][r] - mx) : 0.f;
            e[ni] = val ? (ev - em) : 0.f;
            sum += ev;
        }
        sum += __shfl_xor(sum, 1);
        sum += __shfl_xor(sum, 2);
        sum += __shfl_xor(sum, 4);
        sum += __shfl_xor(sum, 8);
        const float inv = __builtin_amdgcn_rcpf((float)(N - bc) * em + sum);
        pm[r] = em * inv;
#pragma unroll
        for (int ni = 0; ni < 4; ++ni)
            sacc[ni][r] = e[ni] * inv;           // P~ = (e - em)/denom
    }

    // P~ -> LDS fp16 (all 64 cols written; invalid cols are exactly 0)
#pragma unroll
    for (int ni = 0; ni < 4; ++ni)
#pragma unroll
        for (int r = 0; r < 4; ++r)
            Pl[wid][quad * 4 + r][ni * 16 + cl] = f2h(sacc[ni][r]);

    __syncthreads();   // VT scatter complete

    // PV: out(16 rows x 64 dims) = P~ (16x64) . Vband[sbase..sbase+63]
    const int b = bh >> 4, h = bh & 15;
#pragma unroll
    for (int dn = 0; dn < 4; ++dn) {
        f32x4 o = (f32x4){0.f, 0.f, 0.f, 0.f};
#pragma unroll
        for (int k0 = 0; k0 < 64; k0 += 32) {
            const f16x8 a  = *(const f16x8*)&Pl[wid][cl][k0 + quad * 8];
            const f16x8 bb = *(const f16x8*)&VT[dn * 16 + cl][sbase + k0 + quad * 8];
            o = MFMA16(a, bb, o);
        }
        const int d = dn * 16 + cl;
        const float sv = sall[bh * 64 + d];
#pragma unroll
        for (int r = 0; r < 4; ++r) {
            const int n = n0 + wm + quad * 4 + r;
            outp[((size_t)b * N + n) * 1024 + h * 64 + d] = f2h(o[r] + pm[r] * sv);
        }
    }
}

extern "C" void kernel_launch(void* const* d_in, const int* in_sizes, int n_in,
                              void* d_out, int out_size, void* d_ws, size_t ws_size,
                              hipStream_t stream)
{
    const float* x      = (const float*)d_in[0];
    const float* qkv_w  = (const float*)d_in[1];
    const float* proj_w = (const float*)d_in[2];
    const float* proj_b = (const float*)d_in[3];
    const int*   epoch  = (const int*)d_in[4];
    float* out = (float*)d_out;

    const size_t BHND = (size_t)2 * 16 * 2048 * 64;   // 4,194,304
    const size_t XN = 4194304, WN = 3145728;

    ushort* qkv16 = (ushort*)d_ws;            // q|k|v fp16, contiguous
    ushort* q16   = qkv16;
    ushort* k16   = qkv16 + BHND;
    ushort* v16   = qkv16 + 2 * BHND;
    float*  sall  = (float*)(qkv16 + 3 * BHND);   // 2048 floats (pad 4096)
    ushort* x16   = (ushort*)(sall + 4096);
    ushort* w16   = x16 + XN;
    ushort* pw16  = w16 + WN;
    ushort* ao    = x16;   // alias: x16 dead after qkv gemm

    split_all<<<dim3(8192), dim3(256), 0, stream>>>(
        x, qkv_w, proj_w, x16, w16, pw16, sall);

    gemm_mfma<<<dim3(24, 32), dim3(256), 0, stream>>>(x16, w16, qkv16, sall, 1024);

    attn_mfma<<<dim3(512), dim3(512), 0, stream>>>(q16, k16, v16, sall, ao, epoch);

    gemm_proj<<<dim3(8, 64), dim3(256), 0, stream>>>(ao, pw16, proj_b, out);
}

// Round 3
// 145.289 us; speedup vs baseline: 1.0194x; 1.0194x over previous
//
#include <hip/hip_runtime.h>
#include <cstddef>

// ---------------------------------------------------------------------------
// B=2, N=2048, C=1024, H=16, Dh=64, scale = Dh//H = 4
// 4-launch ALL-FP16 pipeline:
//   split_all:     x, qkv_w, proj_w -> fp16 (also zeroes sall)
//   gemm_qkv_pipe: qkv GEMM, 256x192 tile, BK=32, 5-buffer counted-vmcnt
//                  pipeline (prefetch distance 4, never drains vmcnt to 0);
//                  per-column-group S_all atomic accumulation in epilogue
//   attn_mfma:     S=QK^T fp16 MFMA, 128 q-rows/block (512 thr, 8 waves),
//                  per-wave 64-wide K-window, exact softmax w/ masked-logit
//                  (=1e-9) fold, P fp16 -> PV MFMA vs LDS V^T
//   gemm_proj:     64x128 tiles, BK=128 four-plane
// ---------------------------------------------------------------------------

typedef _Float16 f16x8 __attribute__((ext_vector_type(8)));
typedef float    f32x4 __attribute__((ext_vector_type(4)));

#define MFMA16(a, b, c) __builtin_amdgcn_mfma_f32_16x16x32_f16((a), (b), (c), 0, 0, 0)

__device__ __forceinline__ void gl_lds16(const void* g, void* l) {
    __builtin_amdgcn_global_load_lds(
        (const __attribute__((address_space(1))) void*)g,
        (__attribute__((address_space(3))) void*)l, 16, 0, 0);
}

__device__ __forceinline__ ushort f2h(float f) {
    _Float16 h = (_Float16)f;
    return *(ushort*)&h;
}

// ---------------------------------------------------------------------------
// fused fp32 -> fp16 conversion for all three tensors + sall zeroing.
// ---------------------------------------------------------------------------
__global__ void split_all(const float* __restrict__ x,
                          const float* __restrict__ qkvw,
                          const float* __restrict__ projw,
                          ushort* __restrict__ x16,
                          ushort* __restrict__ w16,
                          ushort* __restrict__ pw16,
                          float* __restrict__ sall)
{
    const int i = blockIdx.x * 256 + threadIdx.x;
    if (i < 512) ((float4*)sall)[i] = make_float4(0.f, 0.f, 0.f, 0.f);
    const float* src; ushort* dst; int j;
    if (i < 1048576)      { src = x;     dst = x16;  j = i; }
    else if (i < 1835008) { src = qkvw;  dst = w16;  j = i - 1048576; }
    else                  { src = projw; dst = pw16; j = i - 1835008; }

    float4 v = ((const float4*)src)[j];
    ((ushort4*)dst)[j] = make_ushort4(f2h(v.x), f2h(v.y), f2h(v.z), f2h(v.w));
}

// ---------------------------------------------------------------------------
// qkv GEMM, counted-vmcnt pipeline.
// Tile 256(M) x 192(N) x K=1024, BK=32. Grid 16x16 = 256 blocks (1/CU).
// 8 waves = 2M x 4N; per-wave 128x48 = 8x3 16x16 frags; 24 MFMA / K-tile.
// LDS: 5 K-tile buffers of 28 KB (A 256x32 fp16 = 16 KB, B 192x32 = 12 KB)
//      + 4 KB scratch = 144 KB. Prefetch distance 4; steady-state wait is
//      s_waitcnt vmcnt(12) (3 tiles x 4 loads in flight) -- never 0 in loop.
// Per-thread loads/tile = 4 (uniform across waves; waves 4-7 mirror the B
// tail chunk into scratch so per-wave vmcnt counts stay uniform).
// T2 swizzle: physical 16B slot = logical_slot ^ ((row>>1)&3), applied on
// BOTH the pre-swizzled global source and the ds_read address (rule #21).
// ---------------------------------------------------------------------------
__global__ __launch_bounds__(512, 2) void gemm_qkv_pipe(
    const ushort* __restrict__ A_g, const ushort* __restrict__ W_g,
    ushort* __restrict__ out16, float* __restrict__ sall)
{
    const int K = 1024;
    __shared__ ushort sm[73728];   // 5*14336 + 2048 scratch (ushort units)

    const int tid  = threadIdx.x;
    const int wid  = tid >> 6;
    const int lane = tid & 63;
    const int quad = lane >> 4;
    const int cl   = lane & 15;

    // XCD-aware swizzle (bijective: 256 = 8*32)
    const int bsw = (blockIdx.x & 7) * 32 + (blockIdx.x >> 3);
    const int m0 = (bsw >> 4) * 256;
    const int n0 = (bsw & 15) * 192;

    const int wr = wid >> 2;       // 0..1  M wave group
    const int wc = wid & 3;        // 0..3  N wave group

    // ---- staging setup: 4 chunks/tile, each 8 KB = 512 lanes x 16 B ----
    const int lrow = lane >> 2;    // row within wave's 16-row span
    const int sl   = lane & 3;     // physical 16B slot within 64B row
    const int rA1 = wid * 16 + lrow;              // A rows   0..127
    const int rA2 = 128 + rA1;                    // A rows 128..255
    const int rB1 = wid * 16 + lrow;              // B rows   0..127
    const int rB2 = 128 + (wid & 3) * 16 + lrow;  // B rows 128..191

    const ushort* sA1 = A_g + (size_t)(m0 + rA1) * K + ((sl ^ ((rA1 >> 1) & 3)) * 8);
    const ushort* sA2 = A_g + (size_t)(m0 + rA2) * K + ((sl ^ ((rA2 >> 1) & 3)) * 8);
    const ushort* sB1 = W_g + (size_t)(n0 + rB1) * K + ((sl ^ ((rB1 >> 1) & 3)) * 8);
    const ushort* sB2 = W_g + (size_t)(n0 + rB2) * K + ((sl ^ ((rB2 >> 1) & 3)) * 8);

    const int dA1 = wid * 512;             // LDS dests (wave-uniform, ushorts)
    const int dA2 = 4096 + wid * 512;
    const int dB1 = 8192 + wid * 512;

    // ---- ds_read offsets (ushort units, relative to buffer base) ----
    int aoff[8], boff[3];
#pragma unroll
    for (int mg = 0; mg < 8; ++mg) {
        const int row = wr * 128 + mg * 16 + cl;
        aoff[mg] = row * 32 + ((quad ^ ((row >> 1) & 3)) * 8);
    }
#pragma unroll
    for (int ng = 0; ng < 3; ++ng) {
        const int row = wc * 48 + ng * 16 + cl;
        boff[ng] = 8192 + row * 32 + ((quad ^ ((row >> 1) & 3)) * 8);
    }

    f32x4 acc[8][3];
#pragma unroll
    for (int mg = 0; mg < 8; ++mg)
#pragma unroll
        for (int ng = 0; ng < 3; ++ng) acc[mg][ng] = (f32x4){0.f, 0.f, 0.f, 0.f};

    int kst = 0;   // staged-tile K offset (ushort units; +32 per tile)

#define STAGE_T(BUF) do {                                                    \
    const int bo_ = (BUF) * 14336;                                           \
    gl_lds16(sA1 + kst, sm + bo_ + dA1);                                     \
    gl_lds16(sA2 + kst, sm + bo_ + dA2);                                     \
    gl_lds16(sB1 + kst, sm + bo_ + dB1);                                     \
    ushort* pB2_ = (wid < 4) ? (sm + bo_ + 12288 + wid * 512)                \
                             : (sm + 71680 + (wid & 3) * 512);               \
    gl_lds16(sB2 + kst, pB2_);                                               \
    kst += 32;                                                               \
} while (0)

#define COMPUTE_T(BUF) do {                                                  \
    const int co_ = (BUF) * 14336;                                           \
    f16x8 af[8]; f16x8 bf[3];                                                \
    _Pragma("unroll")                                                        \
    for (int mg = 0; mg < 8; ++mg) af[mg] = *(const f16x8*)&sm[co_ + aoff[mg]]; \
    _Pragma("unroll")                                                        \
    for (int ng = 0; ng < 3; ++ng) bf[ng] = *(const f16x8*)&sm[co_ + boff[ng]]; \
    __builtin_amdgcn_s_setprio(1);                                           \
    _Pragma("unroll")                                                        \
    for (int mg = 0; mg < 8; ++mg)                                           \
        _Pragma("unroll")                                                    \
        for (int ng = 0; ng < 3; ++ng)                                       \
            acc[mg][ng] = MFMA16(af[mg], bf[ng], acc[mg][ng]);               \
    __builtin_amdgcn_s_setprio(0);                                           \
} while (0)

#define WAITBAR(N) do {                                                      \
    asm volatile("s_waitcnt vmcnt(" #N ")" ::: "memory");                    \
    __builtin_amdgcn_s_barrier();                                            \
    asm volatile("" ::: "memory");                                           \
} while (0)

    // prologue: fill 4 buffers (16 loads/thread in flight)
    STAGE_T(0); STAGE_T(1); STAGE_T(2); STAGE_T(3);

    int bc = 0, bs = 4;
    for (int t = 0; t < 28; ++t) {
        WAITBAR(12);               // tile t complete; t+1..t+3 stay in flight
        STAGE_T(bs);               // tile t+4 into buffer freed at t-1
        COMPUTE_T(bc);
        bc = (bc == 4) ? 0 : bc + 1;
        bs = (bs == 4) ? 0 : bs + 1;
    }
    WAITBAR(12); COMPUTE_T(bc); bc = (bc == 4) ? 0 : bc + 1;   // t=28
    WAITBAR(8);  COMPUTE_T(bc); bc = (bc == 4) ? 0 : bc + 1;   // t=29
    WAITBAR(4);  COMPUTE_T(bc); bc = (bc == 4) ? 0 : bc + 1;   // t=30
    WAITBAR(0);  COMPUTE_T(bc);                                // t=31

#undef STAGE_T
#undef COMPUTE_T
#undef WAITBAR

    // ---- epilogue: scatter fp16 into q|k|v [3][B,H,N,64] ----
#pragma unroll
    for (int mg = 0; mg < 8; ++mg)
#pragma unroll
        for (int r = 0; r < 4; ++r) {
            const int gm = m0 + wr * 128 + mg * 16 + quad * 4 + r;
            const int bq = gm >> 11;
            const int nn = gm & 2047;
#pragma unroll
            for (int ng = 0; ng < 3; ++ng) {
                const int gn = n0 + wc * 48 + ng * 16 + cl;
                const int sq = gn >> 10;          // 0:q 1:k 2:v
                const int h  = (gn >> 6) & 15;
                const int dh = gn & 63;
                out16[(size_t)sq * 4194304u + (((size_t)bq * 16 + h) * 2048 + nn) * 64 + dh]
                    = f2h(acc[mg][ng][r]);
            }
        }

    // ---- S_all partials for v columns (gn >= 2048); 16-col groups are
    //      uniform wrt the 2048 boundary and h (both 16-aligned tests) ----
    const int bq2 = (m0 + wr * 128) >> 11;        // wave's 128 rows: one b
#pragma unroll
    for (int ng = 0; ng < 3; ++ng) {
        const int gbase = n0 + wc * 48 + ng * 16;
        if (gbase >= 2048) {
            float ps = 0.f;
#pragma unroll
            for (int mg = 0; mg < 8; ++mg)
#pragma unroll
                for (int r = 0; r < 4; ++r) ps += acc[mg][ng][r];
            ps += __shfl_xor(ps, 16);
            ps += __shfl_xor(ps, 32);
            if (quad == 0) {
                const int h = (gbase >> 6) & 15;
                atomicAdd(&sall[(bq2 * 16 + h) * 64 + (gbase & 63) + cl], ps);
            }
        }
    }
}

// ---------------------------------------------------------------------------
// Proj GEMM, 64x128 tiles (512 blocks = 2/CU), BK=128 four-plane (48 KB LDS).
// ---------------------------------------------------------------------------
__global__ __launch_bounds__(256, 2) void gemm_proj(
    const ushort* __restrict__ A_g, const ushort* __restrict__ W_g,
    const float* __restrict__ bias, float* __restrict__ out)
{
    const int K = 1024, Nout = 1024;
    __shared__ ushort smem[24576];

    const int tid  = threadIdx.x;
    const int wid  = tid >> 6;
    const int lane = tid & 63;
    const int quad = lane >> 4;
    const int cl   = lane & 15;
    const int m0 = blockIdx.y * 64;
    const int n0 = blockIdx.x * 128;
    const int wm = (wid & 1) * 32;
    const int wn = (wid >> 1) * 64;

    const int srow = lane >> 2;
    const int scol = (lane & 3) * 8;

    f32x4 acc[2][4];
#pragma unroll
    for (int i = 0; i < 2; ++i)
#pragma unroll
        for (int j = 0; j < 4; ++j) acc[i][j] = (f32x4){0.f, 0.f, 0.f, 0.f};

    for (int k0 = 0; k0 < K; k0 += 128) {
#pragma unroll
        for (int c = 0; c < 12; ++c) {
            const int cid = wid * 12 + c;
            const ushort* s; ushort* d; int rr, pl;
            if (cid < 16) {
                pl = cid >> 2;
                const int ch = cid & 3;
                s = A_g; rr = m0 + ch * 16;
                d = smem + pl * 2048 + ch * 512;
            } else {
                const int wcx = cid - 16;
                pl = wcx >> 3;
                const int ch = wcx & 7;
                s = W_g; rr = n0 + ch * 16;
                d = smem + 8192 + pl * 4096 + ch * 512;
            }
            gl_lds16(s + (size_t)(rr + srow) * K + k0 + pl * 32 + scol, d);
        }
        __syncthreads();

#pragma unroll
        for (int pl = 0; pl < 4; ++pl) {
            const ushort* ASp = smem + pl * 2048;
            const ushort* WSp = smem + 8192 + pl * 4096;
            f16x8 a[2], w[4];
#pragma unroll
            for (int i = 0; i < 2; ++i)
                a[i] = ((const f16x8*)ASp)[(wm + i * 16 + cl) * 4 + quad];
#pragma unroll
            for (int i = 0; i < 4; ++i)
                w[i] = ((const f16x8*)WSp)[(wn + i * 16 + cl) * 4 + quad];
#pragma unroll
            for (int mi = 0; mi < 2; ++mi)
#pragma unroll
                for (int ni = 0; ni < 4; ++ni)
                    acc[mi][ni] = MFMA16(a[mi], w[ni], acc[mi][ni]);
        }
        __syncthreads();
    }

    float bb[4];
#pragma unroll
    for (int ni = 0; ni < 4; ++ni) bb[ni] = bias[n0 + wn + ni * 16 + cl];
#pragma unroll
    for (int mi = 0; mi < 2; ++mi)
#pragma unroll
        for (int r = 0; r < 4; ++r) {
            const int gm = m0 + wm + mi * 16 + quad * 4 + r;
            float* rowp = out + (size_t)gm * Nout;
#pragma unroll
            for (int ni = 0; ni < 4; ++ni) {
                const int gn = n0 + wn + ni * 16 + cl;
                rowp[gn] = acc[mi][ni][r] + bb[ni];
            }
        }
}

// ---------------------------------------------------------------------------
// MFMA flash-band attention (fp16), per-wave 64-wide K-window.
// Block = one (b,h) x 128 q-rows, 8 waves x 16 rows (512 thr).
// ---------------------------------------------------------------------------
__global__ __launch_bounds__(512) void attn_mfma(
    const ushort* __restrict__ qg, const ushort* __restrict__ kg,
    const ushort* __restrict__ vg,
    const float* __restrict__ sall,
    ushort* __restrict__ outp,
    const int* __restrict__ epoch_ptr)
{
    const int N = 2048;
    const int w = (epoch_ptr[0] < 15) ? 16 : 20;

    __shared__ ushort Pl[8][16][72];      // per-wave P~ tile (64 cols + pad)
    __shared__ ushort VT[64][180];        // transposed V band [dim][seq]

    const int tid  = threadIdx.x;
    const int wid  = tid >> 6;            // 0..7
    const int lane = tid & 63;
    const int quad = lane >> 4;
    const int cl   = lane & 15;

    const int bh = blockIdx.x >> 4;       // 32 (b,h) x 16 q-blocks
    const int n0 = (blockIdx.x & 15) << 7;
    const int lo = max(0, n0 - w);
    const int wm = wid << 4;              // 0..112
    const int hi = min(N - 1, n0 + 127 + w);
    const int cnt = hi - lo + 1;          // 144..168

    // zero VT cols [128,180) only (cnt >= 144 guarantees cols <144 get filled)
    for (int t = tid; t < 64 * 26; t += 512) {
        const int row = t / 26;
        const int c2  = 128 + (t - row * 26) * 2;
        *(unsigned*)&VT[row][c2] = 0u;
    }
    __syncthreads();    // zero visible before scatter overwrites [128,cnt)

    // scatter V band (coalesced reads) into VT transposed
    for (int t = tid; t < 168 * 8; t += 512) {
        const int s  = t >> 3;
        const int db = (t & 7) * 8;
        if (s < cnt) {
            uint4 vv = *(const uint4*)(vg + (((size_t)bh * N) + lo + s) * 64 + db);
            VT[db + 0][s] = (ushort)(vv.x & 0xffff); VT[db + 1][s] = (ushort)(vv.x >> 16);
            VT[db + 2][s] = (ushort)(vv.y & 0xffff); VT[db + 3][s] = (ushort)(vv.y >> 16);
            VT[db + 4][s] = (ushort)(vv.z & 0xffff); VT[db + 5][s] = (ushort)(vv.z >> 16);
            VT[db + 6][s] = (ushort)(vv.w & 0xffff); VT[db + 7][s] = (ushort)(vv.w >> 16);
        }
    }

    // per-wave K window base (multiple of 8, in VT coordinates)
    const int jminw = max(0, n0 + wm - w);
    const int sbase = ((jminw - lo) >> 3) << 3;

    const ushort* qp = qg + ((size_t)bh * N + n0 + wm + cl) * 64;
    const f16x8 aq0 = *(const f16x8*)(qp + quad * 8);
    const f16x8 aq1 = *(const f16x8*)(qp + 32 + quad * 8);

    f32x4 sacc[4];
#pragma unroll
    for (int ni = 0; ni < 4; ++ni) {
        int krow = lo + sbase + ni * 16 + cl;
        krow = min(krow, N - 1);                 // clamped rows masked later
        const ushort* kp = kg + ((size_t)bh * N + krow) * 64;
        const f16x8 bk0 = *(const f16x8*)(kp + quad * 8);
        const f16x8 bk1 = *(const f16x8*)(kp + 32 + quad * 8);
        f32x4 s = (f32x4){0.f, 0.f, 0.f, 0.f};
        s = MFMA16(aq0, bk0, s);
        s = MFMA16(aq1, bk1, s);
        sacc[ni] = s;
    }
    // fold scale=4 once (exact power of two)
#pragma unroll
    for (int ni = 0; ni < 4; ++ni) sacc[ni] *= 4.0f;

    float pm[4];
#pragma unroll
    for (int r = 0; r < 4; ++r) {
        const int n = n0 + wm + quad * 4 + r;
        const int jlo = max(0, n - w), jhi = min(N - 1, n + w);
        const int bc = jhi - jlo + 1;
        float mx = 1e-9f;
#pragma unroll
        for (int ni = 0; ni < 4; ++ni) {
            const int j = lo + sbase + ni * 16 + cl;
            const bool val = (j >= n - w) && (j <= n + w) && (j < N);
            const float sv = sacc[ni][r];
            if (val) mx = fmaxf(mx, sv);
        }
        mx = fmaxf(mx, __shfl_xor(mx, 1));
        mx = fmaxf(mx, __shfl_xor(mx, 2));
        mx = fmaxf(mx, __shfl_xor(mx, 4));
        mx = fmaxf(mx, __shfl_xor(mx, 8));
        const float em = __expf(1e-9f - mx);
        float e[4];
        float sum = 0.f;
#pragma unroll
        for (int ni = 0; ni < 4; ++ni) {
            const int j = lo + sbase + ni * 16 + cl;
            const bool val = (j >= n - w) && (j <= n + w) && (j < N);
            const float ev = val ? __expf(sacc[ni][r] - mx) : 0.f;
            e[ni] = val ? (ev - em) : 0.f;
            sum += ev;
        }
        sum += __shfl_xor(sum, 1);
        sum += __shfl_xor(sum, 2);
        sum += __shfl_xor(sum, 4);
        sum += __shfl_xor(sum, 8);
        const float inv = __builtin_amdgcn_rcpf((float)(N - bc) * em + sum);
        pm[r] = em * inv;
#pragma unroll
        for (int ni = 0; ni < 4; ++ni)
            sacc[ni][r] = e[ni] * inv;           // P~ = (e - em)/denom
    }

    // P~ -> LDS fp16 (all 64 cols written; invalid cols are exactly 0)
#pragma unroll
    for (int ni = 0; ni < 4; ++ni)
#pragma unroll
        for (int r = 0; r < 4; ++r)
            Pl[wid][quad * 4 + r][ni * 16 + cl] = f2h(sacc[ni][r]);

    __syncthreads();   // VT scatter complete

    // PV: out(16 rows x 64 dims) = P~ (16x64) . Vband[sbase..sbase+63]
    const int b = bh >> 4, h = bh & 15;
#pragma unroll
    for (int dn = 0; dn < 4; ++dn) {
        f32x4 o = (f32x4){0.f, 0.f, 0.f, 0.f};
#pragma unroll
        for (int k0 = 0; k0 < 64; k0 += 32) {
            const f16x8 a  = *(const f16x8*)&Pl[wid][cl][k0 + quad * 8];
            const f16x8 bb = *(const f16x8*)&VT[dn * 16 + cl][sbase + k0 + quad * 8];
            o = MFMA16(a, bb, o);
        }
        const int d = dn * 16 + cl;
        const float sv = sall[bh * 64 + d];
#pragma unroll
        for (int r = 0; r < 4; ++r) {
            const int n = n0 + wm + quad * 4 + r;
            outp[((size_t)b * N + n) * 1024 + h * 64 + d] = f2h(o[r] + pm[r] * sv);
        }
    }
}

extern "C" void kernel_launch(void* const* d_in, const int* in_sizes, int n_in,
                              void* d_out, int out_size, void* d_ws, size_t ws_size,
                              hipStream_t stream)
{
    const float* x      = (const float*)d_in[0];
    const float* qkv_w  = (const float*)d_in[1];
    const float* proj_w = (const float*)d_in[2];
    const float* proj_b = (const float*)d_in[3];
    const int*   epoch  = (const int*)d_in[4];
    float* out = (float*)d_out;

    const size_t BHND = (size_t)2 * 16 * 2048 * 64;   // 4,194,304
    const size_t XN = 4194304, WN = 3145728;

    ushort* qkv16 = (ushort*)d_ws;            // q|k|v fp16, contiguous
    ushort* q16   = qkv16;
    ushort* k16   = qkv16 + BHND;
    ushort* v16   = qkv16 + 2 * BHND;
    float*  sall  = (float*)(qkv16 + 3 * BHND);   // 2048 floats (pad 4096)
    ushort* x16   = (ushort*)(sall + 4096);
    ushort* w16   = x16 + XN;
    ushort* pw16  = w16 + WN;
    ushort* ao    = x16;   // alias: x16 dead after qkv gemm

    split_all<<<dim3(8192), dim3(256), 0, stream>>>(
        x, qkv_w, proj_w, x16, w16, pw16, sall);

    gemm_qkv_pipe<<<dim3(256), dim3(512), 0, stream>>>(x16, w16, qkv16, sall);

    attn_mfma<<<dim3(512), dim3(512), 0, stream>>>(q16, k16, v16, sall, ao, epoch);

    gemm_proj<<<dim3(8, 64), dim3(256), 0, stream>>>(ao, pw16, proj_b, out);
}

// Round 4
// 143.075 us; speedup vs baseline: 1.0352x; 1.0155x over previous
//
#include <hip/hip_runtime.h>
#include <cstddef>

// ---------------------------------------------------------------------------
// B=2, N=2048, C=1024, H=16, Dh=64, scale = Dh//H = 4
// 4-launch ALL-FP16 pipeline:
//   split_all:      x, qkv_w, proj_w -> fp16 (also zeroes sall)
//   gemm_qkv_pipe:  qkv GEMM, 256x192 tile, BK=32, 5-buffer counted-vmcnt
//                   pipeline (prefetch distance 4, never drains vmcnt to 0);
//                   per-column-group S_all atomic accumulation in epilogue
//   attn_mfma:      S=QK^T fp16 MFMA, 128 q-rows/block (512 thr, 8 waves),
//                   per-wave 64-wide K-window, exact softmax w/ masked-logit
//                   (=1e-9) fold, P fp16 -> PV MFMA vs LDS V^T
//   gemm_proj_pipe: proj GEMM, 128x128 tile, BK=32, same 5-buffer
//                   counted-vmcnt pipeline (80 KB LDS, 2 blocks/CU)
// ---------------------------------------------------------------------------

typedef _Float16 f16x8 __attribute__((ext_vector_type(8)));
typedef float    f32x4 __attribute__((ext_vector_type(4)));

#define MFMA16(a, b, c) __builtin_amdgcn_mfma_f32_16x16x32_f16((a), (b), (c), 0, 0, 0)

__device__ __forceinline__ void gl_lds16(const void* g, void* l) {
    __builtin_amdgcn_global_load_lds(
        (const __attribute__((address_space(1))) void*)g,
        (__attribute__((address_space(3))) void*)l, 16, 0, 0);
}

__device__ __forceinline__ ushort f2h(float f) {
    _Float16 h = (_Float16)f;
    return *(ushort*)&h;
}

// ---------------------------------------------------------------------------
// fused fp32 -> fp16 conversion for all three tensors + sall zeroing.
// ---------------------------------------------------------------------------
__global__ void split_all(const float* __restrict__ x,
                          const float* __restrict__ qkvw,
                          const float* __restrict__ projw,
                          ushort* __restrict__ x16,
                          ushort* __restrict__ w16,
                          ushort* __restrict__ pw16,
                          float* __restrict__ sall)
{
    const int i = blockIdx.x * 256 + threadIdx.x;
    if (i < 512) ((float4*)sall)[i] = make_float4(0.f, 0.f, 0.f, 0.f);
    const float* src; ushort* dst; int j;
    if (i < 1048576)      { src = x;     dst = x16;  j = i; }
    else if (i < 1835008) { src = qkvw;  dst = w16;  j = i - 1048576; }
    else                  { src = projw; dst = pw16; j = i - 1835008; }

    float4 v = ((const float4*)src)[j];
    ((ushort4*)dst)[j] = make_ushort4(f2h(v.x), f2h(v.y), f2h(v.z), f2h(v.w));
}

// ---------------------------------------------------------------------------
// qkv GEMM, counted-vmcnt pipeline.
// Tile 256(M) x 192(N) x K=1024, BK=32. Grid 16x16 = 256 blocks (1/CU).
// 8 waves = 2M x 4N; per-wave 128x48 = 8x3 16x16 frags; 24 MFMA / K-tile.
// LDS: 5 K-tile buffers of 28 KB + 4 KB scratch = 144 KB. Prefetch
// distance 4; steady-state wait is s_waitcnt vmcnt(12) -- never 0 in loop.
// Per-thread loads/tile = 4 (uniform across waves; waves 4-7 mirror the B
// tail chunk into scratch so per-wave vmcnt counts stay uniform).
// T2 swizzle: physical 16B slot = logical_slot ^ ((row>>1)&3), applied on
// BOTH the pre-swizzled global source and the ds_read address (rule #21).
// ---------------------------------------------------------------------------
__global__ __launch_bounds__(512, 2) void gemm_qkv_pipe(
    const ushort* __restrict__ A_g, const ushort* __restrict__ W_g,
    ushort* __restrict__ out16, float* __restrict__ sall)
{
    const int K = 1024;
    __shared__ ushort sm[73728];   // 5*14336 + 2048 scratch (ushort units)

    const int tid  = threadIdx.x;
    const int wid  = tid >> 6;
    const int lane = tid & 63;
    const int quad = lane >> 4;
    const int cl   = lane & 15;

    // XCD-aware swizzle (bijective: 256 = 8*32)
    const int bsw = (blockIdx.x & 7) * 32 + (blockIdx.x >> 3);
    const int m0 = (bsw >> 4) * 256;
    const int n0 = (bsw & 15) * 192;

    const int wr = wid >> 2;       // 0..1  M wave group
    const int wc = wid & 3;        // 0..3  N wave group

    // ---- staging setup: 4 chunks/tile, each 8 KB = 512 lanes x 16 B ----
    const int lrow = lane >> 2;    // row within wave's 16-row span
    const int sl   = lane & 3;     // physical 16B slot within 64B row
    const int rA1 = wid * 16 + lrow;              // A rows   0..127
    const int rA2 = 128 + rA1;                    // A rows 128..255
    const int rB1 = wid * 16 + lrow;              // B rows   0..127
    const int rB2 = 128 + (wid & 3) * 16 + lrow;  // B rows 128..191

    const ushort* sA1 = A_g + (size_t)(m0 + rA1) * K + ((sl ^ ((rA1 >> 1) & 3)) * 8);
    const ushort* sA2 = A_g + (size_t)(m0 + rA2) * K + ((sl ^ ((rA2 >> 1) & 3)) * 8);
    const ushort* sB1 = W_g + (size_t)(n0 + rB1) * K + ((sl ^ ((rB1 >> 1) & 3)) * 8);
    const ushort* sB2 = W_g + (size_t)(n0 + rB2) * K + ((sl ^ ((rB2 >> 1) & 3)) * 8);

    const int dA1 = wid * 512;             // LDS dests (wave-uniform, ushorts)
    const int dA2 = 4096 + wid * 512;
    const int dB1 = 8192 + wid * 512;

    // ---- ds_read offsets (ushort units, relative to buffer base) ----
    int aoff[8], boff[3];
#pragma unroll
    for (int mg = 0; mg < 8; ++mg) {
        const int row = wr * 128 + mg * 16 + cl;
        aoff[mg] = row * 32 + ((quad ^ ((row >> 1) & 3)) * 8);
    }
#pragma unroll
    for (int ng = 0; ng < 3; ++ng) {
        const int row = wc * 48 + ng * 16 + cl;
        boff[ng] = 8192 + row * 32 + ((quad ^ ((row >> 1) & 3)) * 8);
    }

    f32x4 acc[8][3];
#pragma unroll
    for (int mg = 0; mg < 8; ++mg)
#pragma unroll
        for (int ng = 0; ng < 3; ++ng) acc[mg][ng] = (f32x4){0.f, 0.f, 0.f, 0.f};

    int kst = 0;   // staged-tile K offset (ushort units; +32 per tile)

#define STAGE_T(BUF) do {                                                    \
    const int bo_ = (BUF) * 14336;                                           \
    gl_lds16(sA1 + kst, sm + bo_ + dA1);                                     \
    gl_lds16(sA2 + kst, sm + bo_ + dA2);                                     \
    gl_lds16(sB1 + kst, sm + bo_ + dB1);                                     \
    ushort* pB2_ = (wid < 4) ? (sm + bo_ + 12288 + wid * 512)                \
                             : (sm + 71680 + (wid & 3) * 512);               \
    gl_lds16(sB2 + kst, pB2_);                                               \
    kst += 32;                                                               \
} while (0)

#define COMPUTE_T(BUF) do {                                                  \
    const int co_ = (BUF) * 14336;                                           \
    f16x8 af[8]; f16x8 bf[3];                                                \
    _Pragma("unroll")                                                        \
    for (int mg = 0; mg < 8; ++mg) af[mg] = *(const f16x8*)&sm[co_ + aoff[mg]]; \
    _Pragma("unroll")                                                        \
    for (int ng = 0; ng < 3; ++ng) bf[ng] = *(const f16x8*)&sm[co_ + boff[ng]]; \
    __builtin_amdgcn_s_setprio(1);                                           \
    _Pragma("unroll")                                                        \
    for (int mg = 0; mg < 8; ++mg)                                           \
        _Pragma("unroll")                                                    \
        for (int ng = 0; ng < 3; ++ng)                                       \
            acc[mg][ng] = MFMA16(af[mg], bf[ng], acc[mg][ng]);               \
    __builtin_amdgcn_s_setprio(0);                                           \
} while (0)

#define WAITBAR(N) do {                                                      \
    asm volatile("s_waitcnt vmcnt(" #N ")" ::: "memory");                    \
    __builtin_amdgcn_s_barrier();                                            \
    asm volatile("" ::: "memory");                                           \
} while (0)

    // prologue: fill 4 buffers (16 loads/thread in flight)
    STAGE_T(0); STAGE_T(1); STAGE_T(2); STAGE_T(3);

    int bc = 0, bs = 4;
    for (int t = 0; t < 28; ++t) {
        WAITBAR(12);               // tile t complete; t+1..t+3 stay in flight
        STAGE_T(bs);               // tile t+4 into buffer freed at t-1
        COMPUTE_T(bc);
        bc = (bc == 4) ? 0 : bc + 1;
        bs = (bs == 4) ? 0 : bs + 1;
    }
    WAITBAR(12); COMPUTE_T(bc); bc = (bc == 4) ? 0 : bc + 1;   // t=28
    WAITBAR(8);  COMPUTE_T(bc); bc = (bc == 4) ? 0 : bc + 1;   // t=29
    WAITBAR(4);  COMPUTE_T(bc); bc = (bc == 4) ? 0 : bc + 1;   // t=30
    WAITBAR(0);  COMPUTE_T(bc);                                // t=31

#undef STAGE_T
#undef COMPUTE_T

    // ---- epilogue: scatter fp16 into q|k|v [3][B,H,N,64] ----
#pragma unroll
    for (int mg = 0; mg < 8; ++mg)
#pragma unroll
        for (int r = 0; r < 4; ++r) {
            const int gm = m0 + wr * 128 + mg * 16 + quad * 4 + r;
            const int bq = gm >> 11;
            const int nn = gm & 2047;
#pragma unroll
            for (int ng = 0; ng < 3; ++ng) {
                const int gn = n0 + wc * 48 + ng * 16 + cl;
                const int sq = gn >> 10;          // 0:q 1:k 2:v
                const int h  = (gn >> 6) & 15;
                const int dh = gn & 63;
                out16[(size_t)sq * 4194304u + (((size_t)bq * 16 + h) * 2048 + nn) * 64 + dh]
                    = f2h(acc[mg][ng][r]);
            }
        }

    // ---- S_all partials for v columns (gn >= 2048); 16-col groups are
    //      uniform wrt the 2048 boundary and h (both 16-aligned tests) ----
    const int bq2 = (m0 + wr * 128) >> 11;        // wave's 128 rows: one b
#pragma unroll
    for (int ng = 0; ng < 3; ++ng) {
        const int gbase = n0 + wc * 48 + ng * 16;
        if (gbase >= 2048) {
            float ps = 0.f;
#pragma unroll
            for (int mg = 0; mg < 8; ++mg)
#pragma unroll
                for (int r = 0; r < 4; ++r) ps += acc[mg][ng][r];
            ps += __shfl_xor(ps, 16);
            ps += __shfl_xor(ps, 32);
            if (quad == 0) {
                const int h = (gbase >> 6) & 15;
                atomicAdd(&sall[(bq2 * 16 + h) * 64 + (gbase & 63) + cl], ps);
            }
        }
    }
#undef WAITBAR
}

// ---------------------------------------------------------------------------
// Proj GEMM, counted-vmcnt pipeline (same schedule as gemm_qkv_pipe).
// Tile 128(M) x 128(N) x K=1024, BK=32. Grid 256 blocks (32M x 8N, XCD-swz).
// 4 waves = 2M x 2N; per-wave 64x64 = 4x4 frags; 16 MFMA / K-tile.
// LDS: 5 buffers x 16 KB = 80 KB -> 2 blocks/CU. 4 uniform loads/thread/tile
// (A 2 issues + B 2 issues). Prefetch distance 4; steady wait vmcnt(12).
// ---------------------------------------------------------------------------
__global__ __launch_bounds__(256, 2) void gemm_proj_pipe(
    const ushort* __restrict__ A_g, const ushort* __restrict__ W_g,
    const float* __restrict__ bias, float* __restrict__ out)
{
    const int K = 1024, Nout = 1024;
    __shared__ ushort sm[40960];   // 5 * 8192 ushorts (16 KB/buffer)

    const int tid  = threadIdx.x;
    const int wid  = tid >> 6;     // 0..3
    const int lane = tid & 63;
    const int quad = lane >> 4;
    const int cl   = lane & 15;

    // XCD-aware swizzle (bijective: 256 = 8*32)
    const int bsw = (blockIdx.x & 7) * 32 + (blockIdx.x >> 3);
    const int m0 = (bsw >> 3) * 128;     // 0..3968 (32 M-tiles)
    const int n0 = (bsw & 7) * 128;      // 0..896  (8 N-tiles)

    const int wm = (wid & 1) * 64;
    const int wn = (wid >> 1) * 64;

    // ---- staging: A/B each 128x32 fp16 = 8 KB = 2 issues x 4 waves ----
    const int lrow = lane >> 2;
    const int sl   = lane & 3;
    const int r1 = wid * 16 + lrow;        // rows  0..63
    const int r2 = 64 + r1;                // rows 64..127

    const ushort* sA1 = A_g + (size_t)(m0 + r1) * K + ((sl ^ ((r1 >> 1) & 3)) * 8);
    const ushort* sA2 = A_g + (size_t)(m0 + r2) * K + ((sl ^ ((r2 >> 1) & 3)) * 8);
    const ushort* sB1 = W_g + (size_t)(n0 + r1) * K + ((sl ^ ((r1 >> 1) & 3)) * 8);
    const ushort* sB2 = W_g + (size_t)(n0 + r2) * K + ((sl ^ ((r2 >> 1) & 3)) * 8);

    const int dA1 = wid * 512;             // LDS dests (ushort units)
    const int dA2 = 2048 + wid * 512;
    const int dB1 = 4096 + wid * 512;
    const int dB2 = 6144 + wid * 512;

    // ---- ds_read offsets (ushort units, relative to buffer base) ----
    int aoff[4], boff[4];
#pragma unroll
    for (int mg = 0; mg < 4; ++mg) {
        const int row = wm + mg * 16 + cl;
        aoff[mg] = row * 32 + ((quad ^ ((row >> 1) & 3)) * 8);
    }
#pragma unroll
    for (int ng = 0; ng < 4; ++ng) {
        const int row = wn + ng * 16 + cl;
        boff[ng] = 4096 + row * 32 + ((quad ^ ((row >> 1) & 3)) * 8);
    }

    f32x4 acc[4][4];
#pragma unroll
    for (int mg = 0; mg < 4; ++mg)
#pragma unroll
        for (int ng = 0; ng < 4; ++ng) acc[mg][ng] = (f32x4){0.f, 0.f, 0.f, 0.f};

    int kst = 0;

#define STAGE_P(BUF) do {                                                    \
    const int bo_ = (BUF) * 8192;                                            \
    gl_lds16(sA1 + kst, sm + bo_ + dA1);                                     \
    gl_lds16(sA2 + kst, sm + bo_ + dA2);                                     \
    gl_lds16(sB1 + kst, sm + bo_ + dB1);                                     \
    gl_lds16(sB2 + kst, sm + bo_ + dB2);                                     \
    kst += 32;                                                               \
} while (0)

#define COMPUTE_P(BUF) do {                                                  \
    const int co_ = (BUF) * 8192;                                            \
    f16x8 af[4]; f16x8 bf[4];                                                \
    _Pragma("unroll")                                                        \
    for (int mg = 0; mg < 4; ++mg) af[mg] = *(const f16x8*)&sm[co_ + aoff[mg]]; \
    _Pragma("unroll")                                                        \
    for (int ng = 0; ng < 4; ++ng) bf[ng] = *(const f16x8*)&sm[co_ + boff[ng]]; \
    __builtin_amdgcn_s_setprio(1);                                           \
    _Pragma("unroll")                                                        \
    for (int mg = 0; mg < 4; ++mg)                                           \
        _Pragma("unroll")                                                    \
        for (int ng = 0; ng < 4; ++ng)                                       \
            acc[mg][ng] = MFMA16(af[mg], bf[ng], acc[mg][ng]);               \
    __builtin_amdgcn_s_setprio(0);                                           \
} while (0)

#define WAITBAR(N) do {                                                      \
    asm volatile("s_waitcnt vmcnt(" #N ")" ::: "memory");                    \
    __builtin_amdgcn_s_barrier();                                            \
    asm volatile("" ::: "memory");                                           \
} while (0)

    // prologue: fill 4 buffers (16 loads/thread in flight)
    STAGE_P(0); STAGE_P(1); STAGE_P(2); STAGE_P(3);

    int bc = 0, bs = 4;
    for (int t = 0; t < 28; ++t) {
        WAITBAR(12);               // tile t complete; t+1..t+3 stay in flight
        STAGE_P(bs);               // tile t+4 into buffer freed at t-1
        COMPUTE_P(bc);
        bc = (bc == 4) ? 0 : bc + 1;
        bs = (bs == 4) ? 0 : bs + 1;
    }
    WAITBAR(12); COMPUTE_P(bc); bc = (bc == 4) ? 0 : bc + 1;   // t=28
    WAITBAR(8);  COMPUTE_P(bc); bc = (bc == 4) ? 0 : bc + 1;   // t=29
    WAITBAR(4);  COMPUTE_P(bc); bc = (bc == 4) ? 0 : bc + 1;   // t=30
    WAITBAR(0);  COMPUTE_P(bc);                                // t=31

#undef STAGE_P
#undef COMPUTE_P
#undef WAITBAR

    float bb[4];
#pragma unroll
    for (int ng = 0; ng < 4; ++ng) bb[ng] = bias[n0 + wn + ng * 16 + cl];
#pragma unroll
    for (int mg = 0; mg < 4; ++mg)
#pragma unroll
        for (int r = 0; r < 4; ++r) {
            const int gm = m0 + wm + mg * 16 + quad * 4 + r;
            float* rowp = out + (size_t)gm * Nout;
#pragma unroll
            for (int ng = 0; ng < 4; ++ng) {
                const int gn = n0 + wn + ng * 16 + cl;
                rowp[gn] = acc[mg][ng][r] + bb[ng];
            }
        }
}

// ---------------------------------------------------------------------------
// MFMA flash-band attention (fp16), per-wave 64-wide K-window.
// Block = one (b,h) x 128 q-rows, 8 waves x 16 rows (512 thr).
// ---------------------------------------------------------------------------
__global__ __launch_bounds__(512) void attn_mfma(
    const ushort* __restrict__ qg, const ushort* __restrict__ kg,
    const ushort* __restrict__ vg,
    const float* __restrict__ sall,
    ushort* __restrict__ outp,
    const int* __restrict__ epoch_ptr)
{
    const int N = 2048;
    const int w = (epoch_ptr[0] < 15) ? 16 : 20;

    __shared__ ushort Pl[8][16][72];      // per-wave P~ tile (64 cols + pad)
    __shared__ ushort VT[64][180];        // transposed V band [dim][seq]

    const int tid  = threadIdx.x;
    const int wid  = tid >> 6;            // 0..7
    const int lane = tid & 63;
    const int quad = lane >> 4;
    const int cl   = lane & 15;

    const int bh = blockIdx.x >> 4;       // 32 (b,h) x 16 q-blocks
    const int n0 = (blockIdx.x & 15) << 7;
    const int lo = max(0, n0 - w);
    const int wm = wid << 4;              // 0..112
    const int hi = min(N - 1, n0 + 127 + w);
    const int cnt = hi - lo + 1;          // 144..168

    // zero VT cols [128,180) only (cnt >= 144 guarantees cols <144 get filled)
    for (int t = tid; t < 64 * 26; t += 512) {
        const int row = t / 26;
        const int c2  = 128 + (t - row * 26) * 2;
        *(unsigned*)&VT[row][c2] = 0u;
    }
    __syncthreads();    // zero visible before scatter overwrites [128,cnt)

    // scatter V band (coalesced reads) into VT transposed
    for (int t = tid; t < 168 * 8; t += 512) {
        const int s  = t >> 3;
        const int db = (t & 7) * 8;
        if (s < cnt) {
            uint4 vv = *(const uint4*)(vg + (((size_t)bh * N) + lo + s) * 64 + db);
            VT[db + 0][s] = (ushort)(vv.x & 0xffff); VT[db + 1][s] = (ushort)(vv.x >> 16);
            VT[db + 2][s] = (ushort)(vv.y & 0xffff); VT[db + 3][s] = (ushort)(vv.y >> 16);
            VT[db + 4][s] = (ushort)(vv.z & 0xffff); VT[db + 5][s] = (ushort)(vv.z >> 16);
            VT[db + 6][s] = (ushort)(vv.w & 0xffff); VT[db + 7][s] = (ushort)(vv.w >> 16);
        }
    }

    // per-wave K window base (multiple of 8, in VT coordinates)
    const int jminw = max(0, n0 + wm - w);
    const int sbase = ((jminw - lo) >> 3) << 3;

    const ushort* qp = qg + ((size_t)bh * N + n0 + wm + cl) * 64;
    const f16x8 aq0 = *(const f16x8*)(qp + quad * 8);
    const f16x8 aq1 = *(const f16x8*)(qp + 32 + quad * 8);

    f32x4 sacc[4];
#pragma unroll
    for (int ni = 0; ni < 4; ++ni) {
        int krow = lo + sbase + ni * 16 + cl;
        krow = min(krow, N - 1);                 // clamped rows masked later
        const ushort* kp = kg + ((size_t)bh * N + krow) * 64;
        const f16x8 bk0 = *(const f16x8*)(kp + quad * 8);
        const f16x8 bk1 = *(const f16x8*)(kp + 32 + quad * 8);
        f32x4 s = (f32x4){0.f, 0.f, 0.f, 0.f};
        s = MFMA16(aq0, bk0, s);
        s = MFMA16(aq1, bk1, s);
        sacc[ni] = s;
    }
    // fold scale=4 once (exact power of two)
#pragma unroll
    for (int ni = 0; ni < 4; ++ni) sacc[ni] *= 4.0f;

    float pm[4];
#pragma unroll
    for (int r = 0; r < 4; ++r) {
        const int n = n0 + wm + quad * 4 + r;
        const int jlo = max(0, n - w), jhi = min(N - 1, n + w);
        const int bc = jhi - jlo + 1;
        float mx = 1e-9f;
#pragma unroll
        for (int ni = 0; ni < 4; ++ni) {
            const int j = lo + sbase + ni * 16 + cl;
            const bool val = (j >= n - w) && (j <= n + w) && (j < N);
            const float sv = sacc[ni][r];
            if (val) mx = fmaxf(mx, sv);
        }
        mx = fmaxf(mx, __shfl_xor(mx, 1));
        mx = fmaxf(mx, __shfl_xor(mx, 2));
        mx = fmaxf(mx, __shfl_xor(mx, 4));
        mx = fmaxf(mx, __shfl_xor(mx, 8));
        const float em = __expf(1e-9f - mx);
        float e[4];
        float sum = 0.f;
#pragma unroll
        for (int ni = 0; ni < 4; ++ni) {
            const int j = lo + sbase + ni * 16 + cl;
            const bool val = (j >= n - w) && (j <= n + w) && (j < N);
            const float ev = val ? __expf(sacc[ni][r] - mx) : 0.f;
            e[ni] = val ? (ev - em) : 0.f;
            sum += ev;
        }
        sum += __shfl_xor(sum, 1);
        sum += __shfl_xor(sum, 2);
        sum += __shfl_xor(sum, 4);
        sum += __shfl_xor(sum, 8);
        const float inv = __builtin_amdgcn_rcpf((float)(N - bc) * em + sum);
        pm[r] = em * inv;
#pragma unroll
        for (int ni = 0; ni < 4; ++ni)
            sacc[ni][r] = e[ni] * inv;           // P~ = (e - em)/denom
    }

    // P~ -> LDS fp16 (all 64 cols written; invalid cols are exactly 0)
#pragma unroll
    for (int ni = 0; ni < 4; ++ni)
#pragma unroll
        for (int r = 0; r < 4; ++r)
            Pl[wid][quad * 4 + r][ni * 16 + cl] = f2h(sacc[ni][r]);

    __syncthreads();   // VT scatter complete

    // PV: out(16 rows x 64 dims) = P~ (16x64) . Vband[sbase..sbase+63]
    const int b = bh >> 4, h = bh & 15;
#pragma unroll
    for (int dn = 0; dn < 4; ++dn) {
        f32x4 o = (f32x4){0.f, 0.f, 0.f, 0.f};
#pragma unroll
        for (int k0 = 0; k0 < 64; k0 += 32) {
            const f16x8 a  = *(const f16x8*)&Pl[wid][cl][k0 + quad * 8];
            const f16x8 bb = *(const f16x8*)&VT[dn * 16 + cl][sbase + k0 + quad * 8];
            o = MFMA16(a, bb, o);
        }
        const int d = dn * 16 + cl;
        const float sv = sall[bh * 64 + d];
#pragma unroll
        for (int r = 0; r < 4; ++r) {
            const int n = n0 + wm + quad * 4 + r;
            outp[((size_t)b * N + n) * 1024 + h * 64 + d] = f2h(o[r] + pm[r] * sv);
        }
    }
}

extern "C" void kernel_launch(void* const* d_in, const int* in_sizes, int n_in,
                              void* d_out, int out_size, void* d_ws, size_t ws_size,
                              hipStream_t stream)
{
    const float* x      = (const float*)d_in[0];
    const float* qkv_w  = (const float*)d_in[1];
    const float* proj_w = (const float*)d_in[2];
    const float* proj_b = (const float*)d_in[3];
    const int*   epoch  = (const int*)d_in[4];
    float* out = (float*)d_out;

    const size_t BHND = (size_t)2 * 16 * 2048 * 64;   // 4,194,304
    const size_t XN = 4194304, WN = 3145728;

    ushort* qkv16 = (ushort*)d_ws;            // q|k|v fp16, contiguous
    ushort* q16   = qkv16;
    ushort* k16   = qkv16 + BHND;
    ushort* v16   = qkv16 + 2 * BHND;
    float*  sall  = (float*)(qkv16 + 3 * BHND);   // 2048 floats (pad 4096)
    ushort* x16   = (ushort*)(sall + 4096);
    ushort* w16   = x16 + XN;
    ushort* pw16  = w16 + WN;
    ushort* ao    = x16;   // alias: x16 dead after qkv gemm

    split_all<<<dim3(8192), dim3(256), 0, stream>>>(
        x, qkv_w, proj_w, x16, w16, pw16, sall);

    gemm_qkv_pipe<<<dim3(256), dim3(512), 0, stream>>>(x16, w16, qkv16, sall);

    attn_mfma<<<dim3(512), dim3(512), 0, stream>>>(q16, k16, v16, sall, ao, epoch);

    gemm_proj_pipe<<<dim3(256), dim3(256), 0, stream>>>(ao, pw16, proj_b, out);
}

// Round 5
// 141.424 us; speedup vs baseline: 1.0473x; 1.0117x over previous
//
#include <hip/hip_runtime.h>
#include <cstddef>

// ---------------------------------------------------------------------------
// B=2, N=2048, C=1024, H=16, Dh=64, scale = Dh//H = 4
// 4-launch ALL-FP16 pipeline:
//   split_all:      x, qkv_w, proj_w -> fp16 (also zeroes sall)
//   gemm_qkv_pipe:  qkv GEMM, 128x192 tile, BK=32, 3-buffer counted-vmcnt
//                   pipeline (prefetch distance 2, never drains vmcnt to 0),
//                   64 KB LDS -> 2 blocks/CU (4 waves/SIMD);
//                   per-column-group S_all atomic accumulation in epilogue
//   attn_mfma:      S=QK^T fp16 MFMA, 128 q-rows/block (512 thr, 8 waves),
//                   per-wave 64-wide K-window, exact softmax w/ masked-logit
//                   (=1e-9) fold, P fp16 -> PV MFMA vs LDS V^T
//   gemm_proj_pipe: proj GEMM, 128x128 tile, BK=32, 5-buffer counted-vmcnt
//                   pipeline (80 KB LDS, 2 blocks/CU)
// ---------------------------------------------------------------------------

typedef _Float16 f16x8 __attribute__((ext_vector_type(8)));
typedef float    f32x4 __attribute__((ext_vector_type(4)));

#define MFMA16(a, b, c) __builtin_amdgcn_mfma_f32_16x16x32_f16((a), (b), (c), 0, 0, 0)

__device__ __forceinline__ void gl_lds16(const void* g, void* l) {
    __builtin_amdgcn_global_load_lds(
        (const __attribute__((address_space(1))) void*)g,
        (__attribute__((address_space(3))) void*)l, 16, 0, 0);
}

__device__ __forceinline__ ushort f2h(float f) {
    _Float16 h = (_Float16)f;
    return *(ushort*)&h;
}

// ---------------------------------------------------------------------------
// fused fp32 -> fp16 conversion for all three tensors + sall zeroing.
// ---------------------------------------------------------------------------
__global__ void split_all(const float* __restrict__ x,
                          const float* __restrict__ qkvw,
                          const float* __restrict__ projw,
                          ushort* __restrict__ x16,
                          ushort* __restrict__ w16,
                          ushort* __restrict__ pw16,
                          float* __restrict__ sall)
{
    const int i = blockIdx.x * 256 + threadIdx.x;
    if (i < 512) ((float4*)sall)[i] = make_float4(0.f, 0.f, 0.f, 0.f);
    const float* src; ushort* dst; int j;
    if (i < 1048576)      { src = x;     dst = x16;  j = i; }
    else if (i < 1835008) { src = qkvw;  dst = w16;  j = i - 1048576; }
    else                  { src = projw; dst = pw16; j = i - 1835008; }

    float4 v = ((const float4*)src)[j];
    ((ushort4*)dst)[j] = make_ushort4(f2h(v.x), f2h(v.y), f2h(v.z), f2h(v.w));
}

// ---------------------------------------------------------------------------
// qkv GEMM, counted-vmcnt pipeline at 2 blocks/CU.
// Tile 128(M) x 192(N) x K=1024, BK=32. Grid 512 blocks (32M x 16N, XCD-swz).
// 8 waves = 2M x 4N; per-wave 64x48 = 4x3 16x16 frags; 12 MFMA / K-tile.
// LDS: 3 K-tile buffers of 20 KB (A 128x32 fp16 = 8 KB, B 192x32 = 12 KB)
//      + 4 KB scratch = 64 KB -> 2 blocks/CU (4 waves/SIMD).
// Prefetch distance 2; steady-state wait is s_waitcnt vmcnt(3) -- never 0
// in the loop. Per-thread loads/tile = 3 (uniform; waves 4-7 mirror the B
// tail chunk into scratch so per-wave vmcnt counts stay uniform).
// Staging into buffer (t+2)%3 at iter t is safe: that buffer held tile t-1,
// whose ds_reads were lgkmcnt-waited before each wave's MFMAs, which precede
// its arrival at this iteration's s_barrier.
// T2 swizzle: physical 16B slot = logical_slot ^ ((row>>1)&3), applied on
// BOTH the pre-swizzled global source and the ds_read address (rule #21).
// __launch_bounds__(512,4) pins VGPR<=128 so both blocks are resident.
// ---------------------------------------------------------------------------
__global__ __launch_bounds__(512, 4) void gemm_qkv_pipe(
    const ushort* __restrict__ A_g, const ushort* __restrict__ W_g,
    ushort* __restrict__ out16, float* __restrict__ sall)
{
    const int K = 1024;
    __shared__ ushort sm[32768];   // 3*10240 + 2048 scratch (ushort units)

    const int tid  = threadIdx.x;
    const int wid  = tid >> 6;
    const int lane = tid & 63;
    const int quad = lane >> 4;
    const int cl   = lane & 15;

    // XCD-aware swizzle (bijective: 512 = 8*64)
    const int bsw = (blockIdx.x & 7) * 64 + (blockIdx.x >> 3);
    const int m0 = (bsw >> 4) * 128;    // 32 m-tiles
    const int n0 = (bsw & 15) * 192;    // 16 n-tiles

    const int wr = wid >> 2;       // 0..1  M wave group (wm = wr*64)
    const int wc = wid & 3;        // 0..3  N wave group (wn = wc*48)

    // ---- staging: 3 chunks/tile, each 8 KB = 512 lanes x 16 B ----
    const int lrow = lane >> 2;    // row within wave's 16-row span
    const int sl   = lane & 3;     // physical 16B slot within 64B row
    const int rA  = wid * 16 + lrow;              // A rows   0..127
    const int rB1 = wid * 16 + lrow;              // B rows   0..127
    const int rB2 = 128 + (wid & 3) * 16 + lrow;  // B rows 128..191

    const ushort* sA  = A_g + (size_t)(m0 + rA ) * K + ((sl ^ ((rA  >> 1) & 3)) * 8);
    const ushort* sB1 = W_g + (size_t)(n0 + rB1) * K + ((sl ^ ((rB1 >> 1) & 3)) * 8);
    const ushort* sB2 = W_g + (size_t)(n0 + rB2) * K + ((sl ^ ((rB2 >> 1) & 3)) * 8);

    const int dA  = wid * 512;             // LDS dests (wave-uniform, ushorts)
    const int dB1 = 4096 + wid * 512;

    // ---- ds_read offsets (ushort units, relative to buffer base) ----
    int aoff[4], boff[3];
#pragma unroll
    for (int mg = 0; mg < 4; ++mg) {
        const int row = wr * 64 + mg * 16 + cl;
        aoff[mg] = row * 32 + ((quad ^ ((row >> 1) & 3)) * 8);
    }
#pragma unroll
    for (int ng = 0; ng < 3; ++ng) {
        const int row = wc * 48 + ng * 16 + cl;
        boff[ng] = 4096 + row * 32 + ((quad ^ ((row >> 1) & 3)) * 8);
    }

    f32x4 acc[4][3];
#pragma unroll
    for (int mg = 0; mg < 4; ++mg)
#pragma unroll
        for (int ng = 0; ng < 3; ++ng) acc[mg][ng] = (f32x4){0.f, 0.f, 0.f, 0.f};

    int kst = 0;   // staged-tile K offset (ushort units; +32 per tile)

#define STAGE_T(BUF) do {                                                    \
    const int bo_ = (BUF) * 10240;                                           \
    gl_lds16(sA  + kst, sm + bo_ + dA);                                      \
    gl_lds16(sB1 + kst, sm + bo_ + dB1);                                     \
    ushort* pB2_ = (wid < 4) ? (sm + bo_ + 8192 + wid * 512)                 \
                             : (sm + 30720 + (wid & 3) * 512);               \
    gl_lds16(sB2 + kst, pB2_);                                               \
    kst += 32;                                                               \
} while (0)

#define COMPUTE_T(BUF) do {                                                  \
    const int co_ = (BUF) * 10240;                                           \
    f16x8 af[4]; f16x8 bf[3];                                                \
    _Pragma("unroll")                                                        \
    for (int mg = 0; mg < 4; ++mg) af[mg] = *(const f16x8*)&sm[co_ + aoff[mg]]; \
    _Pragma("unroll")                                                        \
    for (int ng = 0; ng < 3; ++ng) bf[ng] = *(const f16x8*)&sm[co_ + boff[ng]]; \
    __builtin_amdgcn_s_setprio(1);                                           \
    _Pragma("unroll")                                                        \
    for (int mg = 0; mg < 4; ++mg)                                           \
        _Pragma("unroll")                                                    \
        for (int ng = 0; ng < 3; ++ng)                                       \
            acc[mg][ng] = MFMA16(af[mg], bf[ng], acc[mg][ng]);               \
    __builtin_amdgcn_s_setprio(0);                                           \
} while (0)

#define WAITBAR(N) do {                                                      \
    asm volatile("s_waitcnt vmcnt(" #N ")" ::: "memory");                    \
    __builtin_amdgcn_s_barrier();                                            \
    asm volatile("" ::: "memory");                                           \
} while (0)

    // prologue: fill 2 buffers (6 loads/thread in flight)
    STAGE_T(0); STAGE_T(1);

    int bc = 0, bs = 2;
    for (int t = 0; t < 30; ++t) {
        WAITBAR(3);                // tile t complete; t+1's 3 stay in flight
        STAGE_T(bs);               // tile t+2 into buffer freed at t-1
        COMPUTE_T(bc);
        bc = (bc == 2) ? 0 : bc + 1;
        bs = (bs == 2) ? 0 : bs + 1;
    }
    WAITBAR(3); COMPUTE_T(bc); bc = (bc == 2) ? 0 : bc + 1;    // t=30
    WAITBAR(0); COMPUTE_T(bc);                                 // t=31

#undef STAGE_T
#undef COMPUTE_T

    // ---- epilogue: scatter fp16 into q|k|v [3][B,H,N,64] ----
#pragma unroll
    for (int mg = 0; mg < 4; ++mg)
#pragma unroll
        for (int r = 0; r < 4; ++r) {
            const int gm = m0 + wr * 64 + mg * 16 + quad * 4 + r;
            const int bq = gm >> 11;
            const int nn = gm & 2047;
#pragma unroll
            for (int ng = 0; ng < 3; ++ng) {
                const int gn = n0 + wc * 48 + ng * 16 + cl;
                const int sq = gn >> 10;          // 0:q 1:k 2:v
                const int h  = (gn >> 6) & 15;
                const int dh = gn & 63;
                out16[(size_t)sq * 4194304u + (((size_t)bq * 16 + h) * 2048 + nn) * 64 + dh]
                    = f2h(acc[mg][ng][r]);
            }
        }

    // ---- S_all partials for v columns (gn >= 2048); 16-col groups are
    //      uniform wrt the 2048 boundary and h (both 16-aligned tests) ----
    const int bq2 = (m0 + wr * 64) >> 11;         // wave's 64 rows: one b
#pragma unroll
    for (int ng = 0; ng < 3; ++ng) {
        const int gbase = n0 + wc * 48 + ng * 16;
        if (gbase >= 2048) {
            float ps = 0.f;
#pragma unroll
            for (int mg = 0; mg < 4; ++mg)
#pragma unroll
                for (int r = 0; r < 4; ++r) ps += acc[mg][ng][r];
            ps += __shfl_xor(ps, 16);
            ps += __shfl_xor(ps, 32);
            if (quad == 0) {
                const int h = (gbase >> 6) & 15;
                atomicAdd(&sall[(bq2 * 16 + h) * 64 + (gbase & 63) + cl], ps);
            }
        }
    }
#undef WAITBAR
}

// ---------------------------------------------------------------------------
// Proj GEMM, counted-vmcnt pipeline.
// Tile 128(M) x 128(N) x K=1024, BK=32. Grid 256 blocks (32M x 8N, XCD-swz).
// 4 waves = 2M x 2N; per-wave 64x64 = 4x4 frags; 16 MFMA / K-tile.
// LDS: 5 buffers x 16 KB = 80 KB -> 2 blocks/CU. 4 uniform loads/thread/tile
// (A 2 issues + B 2 issues). Prefetch distance 4; steady wait vmcnt(12).
// ---------------------------------------------------------------------------
__global__ __launch_bounds__(256, 2) void gemm_proj_pipe(
    const ushort* __restrict__ A_g, const ushort* __restrict__ W_g,
    const float* __restrict__ bias, float* __restrict__ out)
{
    const int K = 1024, Nout = 1024;
    __shared__ ushort sm[40960];   // 5 * 8192 ushorts (16 KB/buffer)

    const int tid  = threadIdx.x;
    const int wid  = tid >> 6;     // 0..3
    const int lane = tid & 63;
    const int quad = lane >> 4;
    const int cl   = lane & 15;

    // XCD-aware swizzle (bijective: 256 = 8*32)
    const int bsw = (blockIdx.x & 7) * 32 + (blockIdx.x >> 3);
    const int m0 = (bsw >> 3) * 128;     // 0..3968 (32 M-tiles)
    const int n0 = (bsw & 7) * 128;      // 0..896  (8 N-tiles)

    const int wm = (wid & 1) * 64;
    const int wn = (wid >> 1) * 64;

    // ---- staging: A/B each 128x32 fp16 = 8 KB = 2 issues x 4 waves ----
    const int lrow = lane >> 2;
    const int sl   = lane & 3;
    const int r1 = wid * 16 + lrow;        // rows  0..63
    const int r2 = 64 + r1;                // rows 64..127

    const ushort* sA1 = A_g + (size_t)(m0 + r1) * K + ((sl ^ ((r1 >> 1) & 3)) * 8);
    const ushort* sA2 = A_g + (size_t)(m0 + r2) * K + ((sl ^ ((r2 >> 1) & 3)) * 8);
    const ushort* sB1 = W_g + (size_t)(n0 + r1) * K + ((sl ^ ((r1 >> 1) & 3)) * 8);
    const ushort* sB2 = W_g + (size_t)(n0 + r2) * K + ((sl ^ ((r2 >> 1) & 3)) * 8);

    const int dA1 = wid * 512;             // LDS dests (ushort units)
    const int dA2 = 2048 + wid * 512;
    const int dB1 = 4096 + wid * 512;
    const int dB2 = 6144 + wid * 512;

    // ---- ds_read offsets (ushort units, relative to buffer base) ----
    int aoff[4], boff[4];
#pragma unroll
    for (int mg = 0; mg < 4; ++mg) {
        const int row = wm + mg * 16 + cl;
        aoff[mg] = row * 32 + ((quad ^ ((row >> 1) & 3)) * 8);
    }
#pragma unroll
    for (int ng = 0; ng < 4; ++ng) {
        const int row = wn + ng * 16 + cl;
        boff[ng] = 4096 + row * 32 + ((quad ^ ((row >> 1) & 3)) * 8);
    }

    f32x4 acc[4][4];
#pragma unroll
    for (int mg = 0; mg < 4; ++mg)
#pragma unroll
        for (int ng = 0; ng < 4; ++ng) acc[mg][ng] = (f32x4){0.f, 0.f, 0.f, 0.f};

    int kst = 0;

#define STAGE_P(BUF) do {                                                    \
    const int bo_ = (BUF) * 8192;                                            \
    gl_lds16(sA1 + kst, sm + bo_ + dA1);                                     \
    gl_lds16(sA2 + kst, sm + bo_ + dA2);                                     \
    gl_lds16(sB1 + kst, sm + bo_ + dB1);                                     \
    gl_lds16(sB2 + kst, sm + bo_ + dB2);                                     \
    kst += 32;                                                               \
} while (0)

#define COMPUTE_P(BUF) do {                                                  \
    const int co_ = (BUF) * 8192;                                            \
    f16x8 af[4]; f16x8 bf[4];                                                \
    _Pragma("unroll")                                                        \
    for (int mg = 0; mg < 4; ++mg) af[mg] = *(const f16x8*)&sm[co_ + aoff[mg]]; \
    _Pragma("unroll")                                                        \
    for (int ng = 0; ng < 4; ++ng) bf[ng] = *(const f16x8*)&sm[co_ + boff[ng]]; \
    __builtin_amdgcn_s_setprio(1);                                           \
    _Pragma("unroll")                                                        \
    for (int mg = 0; mg < 4; ++mg)                                           \
        _Pragma("unroll")                                                    \
        for (int ng = 0; ng < 4; ++ng)                                       \
            acc[mg][ng] = MFMA16(af[mg], bf[ng], acc[mg][ng]);               \
    __builtin_amdgcn_s_setprio(0);                                           \
} while (0)

#define WAITBAR(N) do {                                                      \
    asm volatile("s_waitcnt vmcnt(" #N ")" ::: "memory");                    \
    __builtin_amdgcn_s_barrier();                                            \
    asm volatile("" ::: "memory");                                           \
} while (0)

    // prologue: fill 4 buffers (16 loads/thread in flight)
    STAGE_P(0); STAGE_P(1); STAGE_P(2); STAGE_P(3);

    int bc = 0, bs = 4;
    for (int t = 0; t < 28; ++t) {
        WAITBAR(12);               // tile t complete; t+1..t+3 stay in flight
        STAGE_P(bs);               // tile t+4 into buffer freed at t-1
        COMPUTE_P(bc);
        bc = (bc == 4) ? 0 : bc + 1;
        bs = (bs == 4) ? 0 : bs + 1;
    }
    WAITBAR(12); COMPUTE_P(bc); bc = (bc == 4) ? 0 : bc + 1;   // t=28
    WAITBAR(8);  COMPUTE_P(bc); bc = (bc == 4) ? 0 : bc + 1;   // t=29
    WAITBAR(4);  COMPUTE_P(bc); bc = (bc == 4) ? 0 : bc + 1;   // t=30
    WAITBAR(0);  COMPUTE_P(bc);                                // t=31

#undef STAGE_P
#undef COMPUTE_P
#undef WAITBAR

    float bb[4];
#pragma unroll
    for (int ng = 0; ng < 4; ++ng) bb[ng] = bias[n0 + wn + ng * 16 + cl];
#pragma unroll
    for (int mg = 0; mg < 4; ++mg)
#pragma unroll
        for (int r = 0; r < 4; ++r) {
            const int gm = m0 + wm + mg * 16 + quad * 4 + r;
            float* rowp = out + (size_t)gm * Nout;
#pragma unroll
            for (int ng = 0; ng < 4; ++ng) {
                const int gn = n0 + wn + ng * 16 + cl;
                rowp[gn] = acc[mg][ng][r] + bb[ng];
            }
        }
}

// ---------------------------------------------------------------------------
// MFMA flash-band attention (fp16), per-wave 64-wide K-window.
// Block = one (b,h) x 128 q-rows, 8 waves x 16 rows (512 thr).
// ---------------------------------------------------------------------------
__global__ __launch_bounds__(512) void attn_mfma(
    const ushort* __restrict__ qg, const ushort* __restrict__ kg,
    const ushort* __restrict__ vg,
    const float* __restrict__ sall,
    ushort* __restrict__ outp,
    const int* __restrict__ epoch_ptr)
{
    const int N = 2048;
    const int w = (epoch_ptr[0] < 15) ? 16 : 20;

    __shared__ ushort Pl[8][16][72];      // per-wave P~ tile (64 cols + pad)
    __shared__ ushort VT[64][180];        // transposed V band [dim][seq]

    const int tid  = threadIdx.x;
    const int wid  = tid >> 6;            // 0..7
    const int lane = tid & 63;
    const int quad = lane >> 4;
    const int cl   = lane & 15;

    const int bh = blockIdx.x >> 4;       // 32 (b,h) x 16 q-blocks
    const int n0 = (blockIdx.x & 15) << 7;
    const int lo = max(0, n0 - w);
    const int wm = wid << 4;              // 0..112
    const int hi = min(N - 1, n0 + 127 + w);
    const int cnt = hi - lo + 1;          // 144..168

    // zero VT cols [128,180) only (cnt >= 144 guarantees cols <144 get filled)
    for (int t = tid; t < 64 * 26; t += 512) {
        const int row = t / 26;
        const int c2  = 128 + (t - row * 26) * 2;
        *(unsigned*)&VT[row][c2] = 0u;
    }
    __syncthreads();    // zero visible before scatter overwrites [128,cnt)

    // scatter V band (coalesced reads) into VT transposed
    for (int t = tid; t < 168 * 8; t += 512) {
        const int s  = t >> 3;
        const int db = (t & 7) * 8;
        if (s < cnt) {
            uint4 vv = *(const uint4*)(vg + (((size_t)bh * N) + lo + s) * 64 + db);
            VT[db + 0][s] = (ushort)(vv.x & 0xffff); VT[db + 1][s] = (ushort)(vv.x >> 16);
            VT[db + 2][s] = (ushort)(vv.y & 0xffff); VT[db + 3][s] = (ushort)(vv.y >> 16);
            VT[db + 4][s] = (ushort)(vv.z & 0xffff); VT[db + 5][s] = (ushort)(vv.z >> 16);
            VT[db + 6][s] = (ushort)(vv.w & 0xffff); VT[db + 7][s] = (ushort)(vv.w >> 16);
        }
    }

    // per-wave K window base (multiple of 8, in VT coordinates)
    const int jminw = max(0, n0 + wm - w);
    const int sbase = ((jminw - lo) >> 3) << 3;

    const ushort* qp = qg + ((size_t)bh * N + n0 + wm + cl) * 64;
    const f16x8 aq0 = *(const f16x8*)(qp + quad * 8);
    const f16x8 aq1 = *(const f16x8*)(qp + 32 + quad * 8);

    f32x4 sacc[4];
#pragma unroll
    for (int ni = 0; ni < 4; ++ni) {
        int krow = lo + sbase + ni * 16 + cl;
        krow = min(krow, N - 1);                 // clamped rows masked later
        const ushort* kp = kg + ((size_t)bh * N + krow) * 64;
        const f16x8 bk0 = *(const f16x8*)(kp + quad * 8);
        const f16x8 bk1 = *(const f16x8*)(kp + 32 + quad * 8);
        f32x4 s = (f32x4){0.f, 0.f, 0.f, 0.f};
        s = MFMA16(aq0, bk0, s);
        s = MFMA16(aq1, bk1, s);
        sacc[ni] = s;
    }
    // fold scale=4 once (exact power of two)
#pragma unroll
    for (int ni = 0; ni < 4; ++ni) sacc[ni] *= 4.0f;

    float pm[4];
#pragma unroll
    for (int r = 0; r < 4; ++r) {
        const int n = n0 + wm + quad * 4 + r;
        const int jlo = max(0, n - w), jhi = min(N - 1, n + w);
        const int bc = jhi - jlo + 1;
        float mx = 1e-9f;
#pragma unroll
        for (int ni = 0; ni < 4; ++ni) {
            const int j = lo + sbase + ni * 16 + cl;
            const bool val = (j >= n - w) && (j <= n + w) && (j < N);
            const float sv = sacc[ni][r];
            if (val) mx = fmaxf(mx, sv);
        }
        mx = fmaxf(mx, __shfl_xor(mx, 1));
        mx = fmaxf(mx, __shfl_xor(mx, 2));
        mx = fmaxf(mx, __shfl_xor(mx, 4));
        mx = fmaxf(mx, __shfl_xor(mx, 8));
        const float em = __expf(1e-9f - mx);
        float e[4];
        float sum = 0.f;
#pragma unroll
        for (int ni = 0; ni < 4; ++ni) {
            const int j = lo + sbase + ni * 16 + cl;
            const bool val = (j >= n - w) && (j <= n + w) && (j < N);
            const float ev = val ? __expf(sacc[ni][r] - mx) : 0.f;
            e[ni] = val ? (ev - em) : 0.f;
            sum += ev;
        }
        sum += __shfl_xor(sum, 1);
        sum += __shfl_xor(sum, 2);
        sum += __shfl_xor(sum, 4);
        sum += __shfl_xor(sum, 8);
        const float inv = __builtin_amdgcn_rcpf((float)(N - bc) * em + sum);
        pm[r] = em * inv;
#pragma unroll
        for (int ni = 0; ni < 4; ++ni)
            sacc[ni][r] = e[ni] * inv;           // P~ = (e - em)/denom
    }

    // P~ -> LDS fp16 (all 64 cols written; invalid cols are exactly 0)
#pragma unroll
    for (int ni = 0; ni < 4; ++ni)
#pragma unroll
        for (int r = 0; r < 4; ++r)
            Pl[wid][quad * 4 + r][ni * 16 + cl] = f2h(sacc[ni][r]);

    __syncthreads();   // VT scatter complete

    // PV: out(16 rows x 64 dims) = P~ (16x64) . Vband[sbase..sbase+63]
    const int b = bh >> 4, h = bh & 15;
#pragma unroll
    for (int dn = 0; dn < 4; ++dn) {
        f32x4 o = (f32x4){0.f, 0.f, 0.f, 0.f};
#pragma unroll
        for (int k0 = 0; k0 < 64; k0 += 32) {
            const f16x8 a  = *(const f16x8*)&Pl[wid][cl][k0 + quad * 8];
            const f16x8 bb = *(const f16x8*)&VT[dn * 16 + cl][sbase + k0 + quad * 8];
            o = MFMA16(a, bb, o);
        }
        const int d = dn * 16 + cl;
        const float sv = sall[bh * 64 + d];
#pragma unroll
        for (int r = 0; r < 4; ++r) {
            const int n = n0 + wm + quad * 4 + r;
            outp[((size_t)b * N + n) * 1024 + h * 64 + d] = f2h(o[r] + pm[r] * sv);
        }
    }
}

extern "C" void kernel_launch(void* const* d_in, const int* in_sizes, int n_in,
                              void* d_out, int out_size, void* d_ws, size_t ws_size,
                              hipStream_t stream)
{
    const float* x      = (const float*)d_in[0];
    const float* qkv_w  = (const float*)d_in[1];
    const float* proj_w = (const float*)d_in[2];
    const float* proj_b = (const float*)d_in[3];
    const int*   epoch  = (const int*)d_in[4];
    float* out = (float*)d_out;

    const size_t BHND = (size_t)2 * 16 * 2048 * 64;   // 4,194,304
    const size_t XN = 4194304, WN = 3145728;

    ushort* qkv16 = (ushort*)d_ws;            // q|k|v fp16, contiguous
    ushort* q16   = qkv16;
    ushort* k16   = qkv16 + BHND;
    ushort* v16   = qkv16 + 2 * BHND;
    float*  sall  = (float*)(qkv16 + 3 * BHND);   // 2048 floats (pad 4096)
    ushort* x16   = (ushort*)(sall + 4096);
    ushort* w16   = x16 + XN;
    ushort* pw16  = w16 + WN;
    ushort* ao    = x16;   // alias: x16 dead after qkv gemm

    split_all<<<dim3(8192), dim3(256), 0, stream>>>(
        x, qkv_w, proj_w, x16, w16, pw16, sall);

    gemm_qkv_pipe<<<dim3(512), dim3(512), 0, stream>>>(x16, w16, qkv16, sall);

    attn_mfma<<<dim3(512), dim3(512), 0, stream>>>(q16, k16, v16, sall, ao, epoch);

    gemm_proj_pipe<<<dim3(256), dim3(256), 0, stream>>>(ao, pw16, proj_b, out);
}